// Round 10
// baseline (4248.500 us; speedup 1.0000x reference)
//
#include <hip/hip_runtime.h>

#define NROWS 65536
#define DDIM 128
#define NCB 8
#define KCODES 1024
#define BK 128   // codes per LDS chunk

// Exactly-rounded single ops (immune to -ffp-contract fusion)
__device__ __forceinline__ float fadd(float a, float b) { return __fadd_rn(a, b); }
__device__ __forceinline__ float fsub(float a, float b) { return __fsub_rn(a, b); }
__device__ __forceinline__ float fmul(float a, float b) { return __fmul_rn(a, b); }
__device__ __forceinline__ float ffma(float a, float b, float c) { return __fmaf_rn(a, b, c); }

// numpy pairwise_sum (n=128 path): 8 accumulators, r[j] sums a[j], a[j+8], ...
// combine ((r0+r1)+(r2+r3)) + ((r4+r5)+(r6+r7)). Input a[d] = x[d]^2 (rounded mul).
__device__ __forceinline__ float np_sumsq128(const float4* x) {
    float r[8];
#pragma unroll
    for (int j = 0; j < 8; ++j) r[j] = 0.f;
#pragma unroll
    for (int jj = 0; jj < 32; ++jj) {
        float4 v = x[jj];
        int b = (jj & 1) * 4;   // d = 4*jj+c  ->  d mod 8 = b + c
        r[b + 0] = fadd(r[b + 0], fmul(v.x, v.x));
        r[b + 1] = fadd(r[b + 1], fmul(v.y, v.y));
        r[b + 2] = fadd(r[b + 2], fmul(v.z, v.z));
        r[b + 3] = fadd(r[b + 3], fmul(v.w, v.w));
    }
    return fadd(fadd(fadd(r[0], r[1]), fadd(r[2], r[3])),
                fadd(fadd(r[4], r[5]), fadd(r[6], r[7])));
}

// ---------------- Kernel A: per-code squared norms (numpy-pairwise fp32) ----------------
__global__ void rvq_cnorm_kernel(const float* __restrict__ cb,
                                 float* __restrict__ cnorm) {
    int code = blockIdx.x * blockDim.x + threadIdx.x;   // 0 .. 8191
    if (code >= NCB * KCODES) return;
    cnorm[code] = np_sumsq128((const float4*)(cb + (size_t)code * DDIM));
}

// ---------------- Kernel B: main RVQ — faithful fp32 replica of the reference ----------------
// dists[k] = fl( fl(rnorm + cnorm[k]) - fl(2 * dot_seq_fma(res, c_k)) ); argmin first-min;
// residual updated with rounded fp32 subs. One thread = one row.
__global__ __launch_bounds__(256, 1)
void rvq_main_kernel(const float* __restrict__ z,
                     const float* __restrict__ cb,
                     const float* __restrict__ cnorm,
                     float* __restrict__ zq_out,
                     float* __restrict__ codes_out,
                     float* __restrict__ loss_out) {
    __shared__ float4 scode[BK][DDIM / 4];   // 64 KB
    __shared__ float  snorm[BK];
    __shared__ float  lred[256];

    const int tid = threadIdx.x;
    const int row = blockIdx.x * 256 + tid;

    const float4* zp = (const float4*)(z + (size_t)row * DDIM);
    float4 res[DDIM / 4];
#pragma unroll
    for (int j = 0; j < DDIM / 4; ++j) res[j] = zp[j];

    double lsum = 0.0;
    int bestidx[NCB];

    for (int i = 0; i < NCB; ++i) {
        // rnorm exactly as np.sum(residual**2, axis=1): pairwise8 of rounded squares
        const float rnorm = np_sumsq128(res);

        float best = 3.402823466e38f;
        int   bidx = 0;

        for (int c0 = 0; c0 < KCODES; c0 += BK) {
            __syncthreads();   // previous chunk fully consumed
            const float4* g = (const float4*)(cb + ((size_t)i * KCODES + c0) * DDIM);
#pragma unroll
            for (int t = 0; t < (BK * (DDIM / 4)) / 256; ++t) {
                int idx = t * 256 + tid;
                ((float4*)scode)[idx] = g[idx];
            }
            if (tid < BK) snorm[tid] = cnorm[i * KCODES + c0 + tid];
            __syncthreads();

            // 4 codes at a time: 4 independent sequential-FMA chains (BLAS-style dot)
            for (int k = 0; k < BK; k += 4) {
                float a0 = 0.f, a1 = 0.f, a2 = 0.f, a3 = 0.f;
#pragma unroll
                for (int jj = 0; jj < DDIM / 4; ++jj) {
                    float4 r  = res[jj];
                    float4 c0v = scode[k + 0][jj];   // wave-uniform -> broadcast
                    float4 c1v = scode[k + 1][jj];
                    float4 c2v = scode[k + 2][jj];
                    float4 c3v = scode[k + 3][jj];
                    a0 = ffma(r.x, c0v.x, a0); a0 = ffma(r.y, c0v.y, a0);
                    a0 = ffma(r.z, c0v.z, a0); a0 = ffma(r.w, c0v.w, a0);
                    a1 = ffma(r.x, c1v.x, a1); a1 = ffma(r.y, c1v.y, a1);
                    a1 = ffma(r.z, c1v.z, a1); a1 = ffma(r.w, c1v.w, a1);
                    a2 = ffma(r.x, c2v.x, a2); a2 = ffma(r.y, c2v.y, a2);
                    a2 = ffma(r.z, c2v.z, a2); a2 = ffma(r.w, c2v.w, a2);
                    a3 = ffma(r.x, c3v.x, a3); a3 = ffma(r.y, c3v.y, a3);
                    a3 = ffma(r.z, c3v.z, a3); a3 = ffma(r.w, c3v.w, a3);
                }
                // dists with the reference's exact op order, first-min argmin
                float d0 = fsub(fadd(rnorm, snorm[k + 0]), fmul(2.0f, a0));
                float d1 = fsub(fadd(rnorm, snorm[k + 1]), fmul(2.0f, a1));
                float d2 = fsub(fadd(rnorm, snorm[k + 2]), fmul(2.0f, a2));
                float d3 = fsub(fadd(rnorm, snorm[k + 3]), fmul(2.0f, a3));
                if (d0 < best) { best = d0; bidx = c0 + k + 0; }
                if (d1 < best) { best = d1; bidx = c0 + k + 1; }
                if (d2 < best) { best = d2; bidx = c0 + k + 2; }
                if (d3 < best) { best = d3; bidx = c0 + k + 3; }
            }
        }
        bestidx[i] = bidx;

        // residual = residual - cb[bidx]  (plain rounded fp32, as the reference)
        const float4* cw = (const float4*)(cb + ((size_t)i * KCODES + bidx) * DDIM);
        double sq = 0.0;
#pragma unroll
        for (int j = 0; j < DDIM / 4; ++j) {
            float4 c = cw[j];
            res[j].x = fsub(res[j].x, c.x);
            res[j].y = fsub(res[j].y, c.y);
            res[j].z = fsub(res[j].z, c.z);
            res[j].w = fsub(res[j].w, c.w);
            sq += (double)res[j].x * res[j].x + (double)res[j].y * res[j].y
                + (double)res[j].z * res[j].z + (double)res[j].w * res[j].w;
        }
        lsum += sq;   // mean((z_q_i - residual_prev)^2) summand = mean(res_new^2)
    }

    // z_q = z - res_final (loss-free vs reference's accumulation: ~1e-6 << threshold)
    float4* zqp = (float4*)(zq_out + (size_t)row * DDIM);
#pragma unroll
    for (int j = 0; j < DDIM / 4; ++j) {
        float4 zv = zp[j];
        float4 o;
        o.x = fsub(zv.x, res[j].x);
        o.y = fsub(zv.y, res[j].y);
        o.z = fsub(zv.z, res[j].z);
        o.w = fsub(zv.w, res[j].w);
        zqp[j] = o;
    }

    // codes as float values (whole out buffer is read as float32)
    float4* cp = (float4*)(codes_out + (size_t)row * NCB);
    float4 c0v, c1v;
    c0v.x = (float)bestidx[0]; c0v.y = (float)bestidx[1];
    c0v.z = (float)bestidx[2]; c0v.w = (float)bestidx[3];
    c1v.x = (float)bestidx[4]; c1v.y = (float)bestidx[5];
    c1v.z = (float)bestidx[6]; c1v.w = (float)bestidx[7];
    cp[0] = c0v; cp[1] = c1v;

    // Block-reduce loss, one atomic per block
    lred[tid] = (float)lsum;
    __syncthreads();
    for (int s = 128; s > 0; s >>= 1) {
        if (tid < s) lred[tid] += lred[tid + s];
        __syncthreads();
    }
    if (tid == 0) {
        float v = lred[0] * (1.0f / ((float)NROWS * (float)DDIM));
        atomicAdd(&loss_out[0], v);   // commit_loss
        atomicAdd(&loss_out[1], v);   // codebook_loss (numerically identical)
    }
}

extern "C" void kernel_launch(void* const* d_in, const int* in_sizes, int n_in,
                              void* d_out, int out_size, void* d_ws, size_t ws_size,
                              hipStream_t stream) {
    const float* z  = (const float*)d_in[0];
    const float* cb = (const float*)d_in[1];

    float* out        = (float*)d_out;
    float* zq_out     = out;                               // 65536*128
    float* codes_out  = out + (size_t)NROWS * DDIM;        // 65536*8
    float* loss_out   = codes_out + (size_t)NROWS * NCB;   // 2 scalars

    float* cnorm = (float*)d_ws;                           // 8192 floats

    hipMemsetAsync(loss_out, 0, 2 * sizeof(float), stream);

    rvq_cnorm_kernel<<<(NCB * KCODES + 255) / 256, 256, 0, stream>>>(cb, cnorm);
    rvq_main_kernel<<<NROWS / 256, 256, 0, stream>>>(z, cb, cnorm,
                                                     zq_out, codes_out, loss_out);
}